// Round 9
// baseline (11766.559 us; speedup 1.0000x reference)
//
#include <hip/hip_runtime.h>

#define Tt 256
#define NWG 32
#define NT 512
#define ETAf 1e-3f
#define SPIN_CAP (1 << 24)
#define EROW 164

typedef float f4 __attribute__((ext_vector_type(4)));

// ---------------- ws layout (byte offsets) ----------------
// flags: u32[32*32*16] @0 (64KB, zeroed per call); exch: f32[2][32][EROW] @65536;
// S0sh @131072 (128KB); SBsh @262144 (128KB); whist @393216 (256KB, 1KB rows);
// uhist @655360 (128KB, 512B rows). End 786432.

__device__ __forceinline__ unsigned ldflag(const unsigned* p) {
  return __hip_atomic_load(p, __ATOMIC_RELAXED, __HIP_MEMORY_SCOPE_AGENT);
}
__device__ __forceinline__ void stflag(unsigned* p, unsigned v) {
  __hip_atomic_store(p, v, __ATOMIC_RELAXED, __HIP_MEMORY_SCOPE_AGENT);
}
__device__ __forceinline__ f4 ld4_byp(const float* p) {
  f4 r;
  asm volatile("global_load_dwordx4 %0, %1, off sc0 sc1" : "=v"(r) : "v"(p) : "memory");
  return r;
}
__device__ __forceinline__ void st4_byp(float* p, f4 v) {
  asm volatile("global_store_dwordx4 %0, %1, off sc0 sc1" :: "v"(p), "v"(v) : "memory");
}
__device__ __forceinline__ void st1_byp(float* p, float v) {
  asm volatile("global_store_dword %0, %1, off sc0 sc1" :: "v"(p), "v"(v) : "memory");
}
__device__ __forceinline__ void waitvm() { asm volatile("s_waitcnt vmcnt(0)" ::: "memory"); }
__device__ __forceinline__ float wred64(float p) {
  p += __shfl_xor(p, 1); p += __shfl_xor(p, 2); p += __shfl_xor(p, 4);
  p += __shfl_xor(p, 8); p += __shfl_xor(p, 16); p += __shfl_xor(p, 32);
  return p;
}

__global__ void init_ws_kernel(unsigned* w) {
  const int i = blockIdx.x * 256 + threadIdx.x;
  if (i < 32 * 32 * 16) w[i] = 0u;
}

__global__ __launch_bounds__(NT, 1)
void osf_main(const float* __restrict__ Am, const float* __restrict__ Bm,
              const float* __restrict__ Qmat, const float* __restrict__ Rm,
              const float* __restrict__ Km, const float* __restrict__ phi,
              const float* __restrict__ sigma, const float* __restrict__ phis,
              const float* __restrict__ M0, const float* __restrict__ Ms,
              const float* __restrict__ x0, const float* __restrict__ W0,
              float* __restrict__ out, char* __restrict__ ws) {
  unsigned* flags = (unsigned*)ws;
  float* exch  = (float*)(ws + 65536);
  float* S0sh  = (float*)(ws + 131072);
  float* SBsh  = (float*)(ws + 262144);
  float* whist = (float*)(ws + 393216);
  float* uhist = (float*)(ws + 655360);

  const int r = blockIdx.x, tid = threadIdx.x;
  const int n = tid >> 2, dsub = tid & 3;   // M layout: M[r][n][dsub*64+e]
  const int d0 = r * 8;                     // owned d rows
  const float s4h = sqrtf(sqrtf(sigma[r]));

  __shared__ float s_gbuf[32][EROW];   // gathered exchange (row-staggered banks)
  __shared__ float s_wring[32][256];   // w history ring (window)
  __shared__ float s_uring[32][128];   // u history ring (window)
  __shared__ float s_PreV[256][8];     // v-conv pre-block [d][tau]
  __shared__ float s_pvp[2][256];      // PreV partials
  __shared__ float s_PP[20][128];      // P'' staging (win & pre, sequential)
  __shared__ float s_A[8][256];        // A own rows
  __shared__ float s_K[4][256];        // K own rows
  __shared__ float s_S1[8][128];       // phis-row-1 fold of Ms, own d
  __shared__ float s_vb[2][4][65];     // v double buffer (padded)
  __shared__ float s_x[256], s_xn[256], s_W0[256], s_lx[256];
  __shared__ float s_u[128], s_g[128], s_lu[128];
  __shared__ float s_pub[160];
  __shared__ float s_XP[8][8];         // xold pre-block [own d][tau]
  __shared__ float s_fold[8], s_red[8];

  // ---------------- init ----------------
  for (int i = tid; i < 2048; i += NT) ((float*)s_A)[i] = Am[(size_t)d0 * 256 + i];
  for (int i = tid; i < 1024; i += NT) ((float*)s_K)[i] = Km[(size_t)(4 * r) * 256 + i];
  for (int i = tid; i < 256; i += NT) {
    s_W0[i] = W0[(size_t)i * 512];
    s_x[i] = x0[i];
  }
  for (int i = tid; i < 2048; i += NT) ((float*)s_PreV)[i] = 0.f;
  for (int i = tid; i < 520; i += NT) { ((float*)s_vb)[i] = 0.f; }
  for (int i = tid; i < 160; i += NT) s_pub[i] = 0.f;   // xold slots MUST start 0
  if (tid < 64) ((float*)s_XP)[tid] = 0.f;
  for (int i = tid; i < 1024; i += NT) {   // S1 own + shared S0/SB (bypass)
    const int row = i >> 7, nn = i & 127;
    float a0 = 0.f, a1 = 0.f;
    for (int k = 0; k < 20; ++k) {
      const float m = Ms[((size_t)k * 256 + d0 + row) * 128 + nn];
      a0 = fmaf(phis[k], m, a0);
      a1 = fmaf(phis[20 + k], m, a1);
    }
    s_S1[row][nn] = a1;
    st1_byp(S0sh + (size_t)(d0 + row) * 128 + nn, a0);
    st1_byp(SBsh + (size_t)(d0 + row) * 128 + nn, a0 - Bm[(size_t)(d0 + row) * 128 + nn]);
  }
  float Mreg[64];
  {
    const float* mp = M0 + ((size_t)r * 128 + n) * 256 + dsub * 64;
#pragma unroll
    for (int e = 0; e < 64; ++e) Mreg[e] = mp[e];
  }
  waitvm();
  __syncthreads();
  if (tid < 256) s_vb[0][tid >> 6][tid & 63] = s_W0[tid] * phi[r];   // v_0
  __syncthreads();   // all waves' S0/SB stores drained above
  if (tid < 32) stflag(&flags[(r * 32 + tid) * 16], 1u);
  if (tid < 32) {
    const unsigned* fp = &flags[(tid * 32 + r) * 16];
    int guard = 0;
    while (ldflag(fp) < 1u && ++guard < SPIN_CAP) {}
  }
  __syncthreads();

  // ---------------- main loop ----------------
  for (int t = 0; t < Tt; ++t) {
    const unsigned want = (unsigned)(t + 2);
    const int par = t & 1;

    // ===== publish(t): cnp (M-update fused), Ax, Kx; xold slot filled last post =====
    {
      float coef = (t > 0) ? (ETAf * s4h * s_g[n]) : 0.f;
      const float* vc = &s_vb[par][dsub][0];
      const float* vpv = &s_vb[par ^ 1][dsub][0];
      float acc = 0.f;
#pragma unroll
      for (int e = 0; e < 64; ++e) {
        Mreg[e] = fmaf(-coef, vpv[e], Mreg[e]);
        acc = fmaf(Mreg[e], vc[e], acc);
      }
      acc += __shfl_xor(acc, 1); acc += __shfl_xor(acc, 2);
      if (dsub == 0) s_pub[n] = s4h * acc;
    }
    {  // Ax own 8 rows
      const int row = tid >> 6, j = tid & 63;
      float a = s_A[row][j] * s_x[j] + s_A[row][j + 64] * s_x[j + 64] +
                s_A[row][j + 128] * s_x[j + 128] + s_A[row][j + 192] * s_x[j + 192];
      a = wred64(a);
      if (j == 0) s_pub[128 + row] = a;
    }
    if (tid < 256) {  // Kx own 4 rows
      const int row = tid >> 6, j = tid & 63;
      float a = s_K[row][j] * s_x[j] + s_K[row][j + 64] * s_x[j + 64] +
                s_K[row][j + 128] * s_x[j + 128] + s_K[row][j + 192] * s_x[j + 192];
      a = wred64(a);
      if (j == 0) s_pub[136 + row] = a;
    }
    __syncthreads();
    if (tid < 37) st4_byp(exch + ((size_t)par * 32 + r) * EROW + tid * 4,
                          *(const f4*)&s_pub[tid * 4]);
    if (tid < 64) {
      waitvm();
      if (tid < 32) stflag(&flags[(r * 32 + tid) * 16], want);
    }

    // ===== slack(t): O(1)-per-step pre-block + window convolutions =====
    const int shi = (t & ~7) - 3;   // pre-scan upper bound (visibility-safe)
    {  // PreV partials: ages (t+7-s), for target T_v = t+8
      const int d = tid & 255, grp = tid >> 8;
      float a = 0.f;
      for (int s = grp; s <= shi; s += 2)
        a = fmaf(whist[(size_t)s * 256 + d], phi[(size_t)(t + 7 - s) * 32 + r], a);
      s_pvp[grp][d] = a;
    }
    {  // Fwin build: ages (t+1-s), s in [wlo, t-1], from u-ring (LDS)
      const int nn = tid >> 2, kb = (tid & 3) * 5;
      int wlo = ((t + 1) & ~7) - 10; if (wlo < 0) wlo = 0;
      float p5[5] = {0.f, 0.f, 0.f, 0.f, 0.f};
      for (int s = wlo; s <= t - 1; ++s) {
        const float uu = s_uring[s & 31][nn];
        const float* pr = phis + (size_t)(t + 1 - s) * 20 + kb;
#pragma unroll
        for (int i = 0; i < 5; ++i) p5[i] = fmaf(uu, pr[i], p5[i]);
      }
#pragma unroll
      for (int i = 0; i < 5; ++i) s_PP[kb + i][nn] = p5[i];
    }
    __syncthreads();
    {  // Fwin fold -> s_fold (own 8 d)
      const int row = tid >> 6, lane = tid & 63;
      float f = 0.f;
      for (int m = lane; m < 2560; m += 64) {
        const int k = m >> 7, nn = m & 127;
        f = fmaf(Ms[((size_t)k * 256 + d0 + row) * 128 + nn], s_PP[k][nn], f);
      }
      f = wred64(f);
      if (lane == 0) s_fold[row] = f;
    }
    if (t >= 1 && ((t - 1) & 31) == r) {  // deferred loss(t-1) from stash
      const int d = tid >> 1, half = tid & 1;
      const float* qr = Qmat + (size_t)d * 256 + half * 128;
      float qa = 0.f;
#pragma unroll 16
      for (int j = 0; j < 128; ++j) qa = fmaf(qr[j], s_lx[half * 128 + j], qa);
      qa += __shfl_xor(qa, 1);
      float tot = (half == 0) ? qa * s_lx[d] : 0.f;
      {
        const float* rr2 = Rm + (size_t)(tid >> 2) * 128 + (tid & 3) * 32;
        float ra = 0.f;
#pragma unroll
        for (int j = 0; j < 32; ++j) ra = fmaf(rr2[j], s_lu[(tid & 3) * 32 + j], ra);
        ra += __shfl_xor(ra, 1); ra += __shfl_xor(ra, 2);
        if ((tid & 3) == 0) tot += ra * s_lu[tid >> 2];
      }
      tot = wred64(tot);
      if ((tid & 63) == 0) s_red[tid >> 6] = tot;
      __syncthreads();
      if (tid == 0) {
        float ss = 0.f;
        for (int i3 = 0; i3 < 8; ++i3) ss += s_red[i3];
        out[t - 1] = ss;
      }
    }
    __syncthreads();
    {  // PPpre build: ages (t+8-s), s <= shi, from global uhist
      const int nn = tid >> 2, kb = (tid & 3) * 5;
      float p5[5] = {0.f, 0.f, 0.f, 0.f, 0.f};
      for (int s = 0; s <= shi; ++s) {
        const float uu = uhist[(size_t)s * 128 + nn];
        const float* pr = phis + (size_t)(t + 8 - s) * 20 + kb;
#pragma unroll
        for (int i = 0; i < 5; ++i) p5[i] = fmaf(uu, pr[i], p5[i]);
      }
#pragma unroll
      for (int i = 0; i < 5; ++i) s_PP[kb + i][nn] = p5[i];
    }
    __syncthreads();
    {  // XP fold -> s_XP[own d][t&7]
      const int row = tid >> 6, lane = tid & 63;
      float f = 0.f;
      for (int m = lane; m < 2560; m += 64) {
        const int k = m >> 7, nn = m & 127;
        f = fmaf(Ms[((size_t)k * 256 + d0 + row) * 128 + nn], s_PP[k][nn], f);
      }
      f = wred64(f);
      if (lane == 0) s_XP[row][t & 7] = f;
    }

    // ===== poll: 1 poller per replica-flag line =====
    if (tid < 32) {
      const unsigned* fp = &flags[(tid * 32 + r) * 16];
      int guard = 0;
      while (ldflag(fp) < want && ++guard < SPIN_CAP) {}
    }
    __syncthreads();

    // ===== gather: 1184 dwordx4, staggered by producer =====
    {
      const int i0 = tid, i1 = tid + 512, i2 = tid + 1024;
      const int p0 = i0 / 37, c0 = i0 - p0 * 37;
      const int p1 = i1 / 37, c1 = i1 - p1 * 37;
      const int pp0 = (p0 + r) & 31, pp1 = (p1 + r) & 31;
      f4 a0 = ld4_byp(exch + ((size_t)par * 32 + pp0) * EROW + c0 * 4);
      f4 a1 = ld4_byp(exch + ((size_t)par * 32 + pp1) * EROW + c1 * 4);
      f4 a2;
      int pp2 = 0, c2 = 0;
      if (i2 < 1184) {
        const int p2 = i2 / 37; c2 = i2 - p2 * 37; pp2 = (p2 + r) & 31;
        a2 = ld4_byp(exch + ((size_t)par * 32 + pp2) * EROW + c2 * 4);
      }
      waitvm();
      *(f4*)&s_gbuf[pp0][c0 * 4] = a0;
      *(f4*)&s_gbuf[pp1][c1 * 4] = a1;
      if (i2 < 1184) *(f4*)&s_gbuf[pp2][c2 * 4] = a2;
    }
    __syncthreads();

    // ===== post(t): u, g, w, x_{t+1}, v_{t+1}, next xold =====
    if (tid < 128) {
      float s = 0.f;
#pragma unroll 8
      for (int p = 0; p < 32; ++p) s += s_gbuf[p][tid];
      s -= s_gbuf[tid >> 2][136 + (tid & 3)];
      s_u[tid] = s;
      s_uring[t & 31][tid] = s;
      if (r == 0) st1_byp(uhist + (size_t)t * 128 + tid, s);
    }
    __syncthreads();
    if ((t & 31) == r && tid < 256) {   // stash x_t, u_t for deferred loss
      s_lx[tid] = s_x[tid];
      if (tid < 128) s_lu[tid] = s_u[tid];
    }
    {  // g_t = 2 R u_t
      float a = 0.f;
      const float* rr = Rm + (size_t)n * 128 + dsub * 32;
#pragma unroll
      for (int j2 = 0; j2 < 32; ++j2) a = fmaf(rr[j2], s_u[dsub * 32 + j2], a);
      a += __shfl_xor(a, 1); a += __shfl_xor(a, 2);
      if (dsub == 0) s_g[n] = 2.f * a;
    }
    {  // SB·u, S0·u -> w_t, x_{t+1} (replicated)
      const int d = tid >> 1, half = tid & 1;
      const float* sbr = SBsh + (size_t)d * 128 + half * 64;
      const float* s0r = S0sh + (size_t)d * 128 + half * 64;
      const float* ur = s_u + half * 64;
      float asb = 0.f, as0 = 0.f;
#pragma unroll
      for (int j2 = 0; j2 < 64; ++j2) {
        asb = fmaf(sbr[j2], ur[j2], asb);
        as0 = fmaf(s0r[j2], ur[j2], as0);
      }
      asb += __shfl_xor(asb, 1); as0 += __shfl_xor(as0, 1);
      if (half == 0) {
        const float xo = s_gbuf[d >> 3][140 + (d & 7)];
        const float ax = s_gbuf[d >> 3][128 + (d & 7)];
        const float wv = xo + asb - ax;
        s_wring[t & 31][d] = wv;
        s_xn[d] = xo + as0;
        if (r == 0) st1_byp(whist + (size_t)t * 256 + d, wv);
      }
    }
    if (tid < 256) s_PreV[tid][t & 7] = s_pvp[0][tid] + s_pvp[1][tid];
    __syncthreads();
    if (tid < 256) {  // x update + v_{t+1} assembly (pre + window + W0 term)
      const int d = tid, T = t + 1;
      s_x[d] = s_xn[d];
      int lo = (T & ~7) - 10; if (lo < 0) lo = 0;
      float v = s_PreV[d][T & 7] + s_W0[d] * phi[(size_t)T * 32 + r];
      for (int s = lo; s <= t; ++s)
        v = fmaf(s_wring[s & 31][d], phi[(size_t)(t - s) * 32 + r], v);
      s_vb[T & 1][d >> 6][d & 63] = v;
    }
    {  // xold for round t+1: XP-pre + window-fold + S1·u_t
      const int row = tid >> 6, j = tid & 63;
      float a = s_S1[row][j] * s_u[j] + s_S1[row][j + 64] * s_u[j + 64];
      a = wred64(a);
      if (j == 0) s_pub[140 + row] = s_XP[row][(t + 1) & 7] + s_fold[row] + a;
    }
    waitvm();   // drain whist/uhist/exch stores -> flag chain orders them for readers
    __syncthreads();
  }

  // ---------------- final deferred loss (t = 255, r = 31) ----------------
  if (((Tt - 1) & 31) == r) {
    const int d = tid >> 1, half = tid & 1;
    const float* qr = Qmat + (size_t)d * 256 + half * 128;
    float qa = 0.f;
#pragma unroll 16
    for (int j = 0; j < 128; ++j) qa = fmaf(qr[j], s_lx[half * 128 + j], qa);
    qa += __shfl_xor(qa, 1);
    float tot = (half == 0) ? qa * s_lx[d] : 0.f;
    {
      const float* rr2 = Rm + (size_t)(tid >> 2) * 128 + (tid & 3) * 32;
      float ra = 0.f;
#pragma unroll
      for (int j = 0; j < 32; ++j) ra = fmaf(rr2[j], s_lu[(tid & 3) * 32 + j], ra);
      ra += __shfl_xor(ra, 1); ra += __shfl_xor(ra, 2);
      if ((tid & 3) == 0) tot += ra * s_lu[tid >> 2];
    }
    tot = wred64(tot);
    if ((tid & 63) == 0) s_red[tid >> 6] = tot;
    __syncthreads();
    if (tid == 0) {
      float ss = 0.f;
      for (int i3 = 0; i3 < 8; ++i3) ss += s_red[i3];
      out[Tt - 1] = ss;
    }
  }
}

extern "C" void kernel_launch(void* const* d_in, const int* in_sizes, int n_in,
                              void* d_out, int out_size, void* d_ws, size_t ws_size,
                              hipStream_t stream) {
  (void)in_sizes; (void)n_in; (void)out_size; (void)ws_size;
  const float* A   = (const float*)d_in[0];
  const float* B   = (const float*)d_in[1];
  const float* Qm  = (const float*)d_in[2];
  const float* R   = (const float*)d_in[3];
  const float* K   = (const float*)d_in[4];
  const float* phi = (const float*)d_in[5];
  const float* sig = (const float*)d_in[6];
  const float* phs = (const float*)d_in[7];
  const float* M0  = (const float*)d_in[8];
  const float* Ms  = (const float*)d_in[9];
  const float* x0  = (const float*)d_in[10];
  const float* W0  = (const float*)d_in[11];
  // d_in[12] = U0 (zeros, unused)

  // replica flags must be re-zeroed every call (monotone tags)
  init_ws_kernel<<<64, 256, 0, stream>>>((unsigned*)d_ws);
  osf_main<<<NWG, NT, 0, stream>>>(A, B, Qm, R, K, phi, sig, phs, M0, Ms, x0, W0,
                                   (float*)d_out, (char*)d_ws);
}

// Round 10
// 11688.616 us; speedup vs baseline: 1.0067x; 1.0067x over previous
//
#include <hip/hip_runtime.h>

#define Tt 256
#define NWG 32
#define NT 512
#define ETAf 1e-3f
#define SPIN_CAP (1 << 24)
#define EROW 164

typedef float f4 __attribute__((ext_vector_type(4)));

// ---------------- ws layout (byte offsets) ----------------
// flags: u32[32*32*16] @0 (64KB, zeroed per call); exch: f32[2][32][EROW] @65536;
// S0sh @131072 (128KB); SBsh @262144 (128KB); whT[d][s] @393216 (256KB);
// uhT[n][s] @655360 (128KB). End 786432.

__device__ __forceinline__ unsigned ldflag(const unsigned* p) {
  return __hip_atomic_load(p, __ATOMIC_RELAXED, __HIP_MEMORY_SCOPE_AGENT);
}
__device__ __forceinline__ void stflag(unsigned* p, unsigned v) {
  __hip_atomic_store(p, v, __ATOMIC_RELAXED, __HIP_MEMORY_SCOPE_AGENT);
}
__device__ __forceinline__ f4 ld4_byp(const float* p) {
  f4 r;
  asm volatile("global_load_dwordx4 %0, %1, off sc0 sc1" : "=v"(r) : "v"(p) : "memory");
  return r;
}
__device__ __forceinline__ void st4_byp(float* p, f4 v) {
  asm volatile("global_store_dwordx4 %0, %1, off sc0 sc1" :: "v"(p), "v"(v) : "memory");
}
__device__ __forceinline__ void st1_byp(float* p, float v) {
  asm volatile("global_store_dword %0, %1, off sc0 sc1" :: "v"(p), "v"(v) : "memory");
}
__device__ __forceinline__ void waitvm() { asm volatile("s_waitcnt vmcnt(0)" ::: "memory"); }
__device__ __forceinline__ float wred64(float p) {
  p += __shfl_xor(p, 1); p += __shfl_xor(p, 2); p += __shfl_xor(p, 4);
  p += __shfl_xor(p, 8); p += __shfl_xor(p, 16); p += __shfl_xor(p, 32);
  return p;
}

__global__ void init_ws_kernel(unsigned* w) {
  const int i = blockIdx.x * 256 + threadIdx.x;
  if (i < 32 * 32 * 16) w[i] = 0u;
}

__global__ __launch_bounds__(NT, 1)
void osf_main(const float* __restrict__ Am, const float* __restrict__ Bm,
              const float* __restrict__ Qmat, const float* __restrict__ Rm,
              const float* __restrict__ Km, const float* __restrict__ phi,
              const float* __restrict__ sigma, const float* __restrict__ phis,
              const float* __restrict__ M0, const float* __restrict__ Ms,
              const float* __restrict__ x0, const float* __restrict__ W0,
              float* __restrict__ out, char* __restrict__ ws) {
  unsigned* flags = (unsigned*)ws;
  float* exch = (float*)(ws + 65536);
  float* S0sh = (float*)(ws + 131072);
  float* SBsh = (float*)(ws + 262144);
  float* whT  = (float*)(ws + 393216);   // [256 d][256 s]
  float* uhT  = (float*)(ws + 655360);   // [128 n][256 s]

  const int r = blockIdx.x, tid = threadIdx.x;
  const int n = tid >> 2, dsub = tid & 3;   // M layout: M[r][n][dsub*64+e]
  const int d0 = r * 8;                     // owned d rows
  const float s4h = sqrtf(sqrtf(sigma[r]));

  __shared__ float s_gbuf[32][EROW];   // gathered exchange
  __shared__ float s_wring[32][256];   // w history ring (window)
  __shared__ float s_uring[32][128];   // u history ring (window)
  __shared__ float s_PreV[256][8];     // v-conv pre-block [d][tau]
  __shared__ float s_pvp[2][256];      // PreV partials
  __shared__ float s_PP[20][128];      // P'' staging (win & pre, sequential)
  __shared__ float s_phisT[20][288];   // phis transposed: [k][age]
  __shared__ float s_phiT[288];        // own-h phi column: [age]
  __shared__ float s_A[8][256];        // A own rows
  __shared__ float s_K[4][256];        // K own rows
  __shared__ float s_S1[8][128];       // phis-row-1 fold of Ms, own d
  __shared__ float s_vb[2][4][65];     // v double buffer (padded)
  __shared__ float s_x[256], s_xn[256], s_W0[256], s_lx[256];
  __shared__ float s_u[128], s_g[128], s_lu[128];
  __shared__ float s_pub[160];
  __shared__ float s_XP[8][8];         // xold pre-block [own d][tau]
  __shared__ float s_fold[8], s_red[8];

  // ---------------- init ----------------
  for (int i = tid; i < 2048; i += NT) ((float*)s_A)[i] = Am[(size_t)d0 * 256 + i];
  for (int i = tid; i < 1024; i += NT) ((float*)s_K)[i] = Km[(size_t)(4 * r) * 256 + i];
  for (int i = tid; i < 256; i += NT) {
    s_W0[i] = W0[(size_t)i * 512];
    s_x[i] = x0[i];
  }
  for (int i = tid; i < 2048; i += NT) ((float*)s_PreV)[i] = 0.f;
  for (int i = tid; i < 520; i += NT) { ((float*)s_vb)[i] = 0.f; }
  for (int i = tid; i < 160; i += NT) s_pub[i] = 0.f;   // xold slots MUST start 0
  if (tid < 64) ((float*)s_XP)[tid] = 0.f;
  for (int i = tid; i < 20 * 288; i += NT) {   // stage phis transposed by age
    const int k = i / 288, age = i - k * 288;
    s_phisT[k][age] = phis[(size_t)age * 20 + k];
  }
  for (int i = tid; i < 288; i += NT) s_phiT[i] = phi[(size_t)i * 32 + r];
  for (int i = tid; i < 1024; i += NT) {   // S1 own + shared S0/SB (bypass)
    const int row = i >> 7, nn = i & 127;
    float a0 = 0.f, a1 = 0.f;
    for (int k = 0; k < 20; ++k) {
      const float m = Ms[((size_t)k * 256 + d0 + row) * 128 + nn];
      a0 = fmaf(phis[k], m, a0);
      a1 = fmaf(phis[20 + k], m, a1);
    }
    s_S1[row][nn] = a1;
    st1_byp(S0sh + (size_t)(d0 + row) * 128 + nn, a0);
    st1_byp(SBsh + (size_t)(d0 + row) * 128 + nn, a0 - Bm[(size_t)(d0 + row) * 128 + nn]);
  }
  float Mreg[64];
  {
    const float* mp = M0 + ((size_t)r * 128 + n) * 256 + dsub * 64;
#pragma unroll
    for (int e = 0; e < 64; ++e) Mreg[e] = mp[e];
  }
  waitvm();
  __syncthreads();
  if (tid < 256) s_vb[0][tid >> 6][tid & 63] = s_W0[tid] * s_phiT[0];   // v_0
  __syncthreads();   // all waves' S0/SB stores drained above
  if (tid < 32) stflag(&flags[(r * 32 + tid) * 16], 1u);
  if (tid < 32) {
    const unsigned* fp = &flags[(tid * 32 + r) * 16];
    int guard = 0;
    while (ldflag(fp) < 1u && ++guard < SPIN_CAP) {}
  }
  __syncthreads();

  // ---------------- main loop ----------------
  for (int t = 0; t < Tt; ++t) {
    const unsigned want = (unsigned)(t + 2);
    const int par = t & 1;

    // ===== publish(t): cnp (M-update fused), Ax, Kx; xold slot from prev post =====
    {
      float coef = (t > 0) ? (ETAf * s4h * s_g[n]) : 0.f;
      const float* vc = &s_vb[par][dsub][0];
      const float* vpv = &s_vb[par ^ 1][dsub][0];
      float acc = 0.f;
#pragma unroll
      for (int e = 0; e < 64; ++e) {
        Mreg[e] = fmaf(-coef, vpv[e], Mreg[e]);
        acc = fmaf(Mreg[e], vc[e], acc);
      }
      acc += __shfl_xor(acc, 1); acc += __shfl_xor(acc, 2);
      if (dsub == 0) s_pub[n] = s4h * acc;
    }
    {  // Ax own 8 rows
      const int row = tid >> 6, j = tid & 63;
      float a = s_A[row][j] * s_x[j] + s_A[row][j + 64] * s_x[j + 64] +
                s_A[row][j + 128] * s_x[j + 128] + s_A[row][j + 192] * s_x[j + 192];
      a = wred64(a);
      if (j == 0) s_pub[128 + row] = a;
    }
    if (tid < 256) {  // Kx own 4 rows
      const int row = tid >> 6, j = tid & 63;
      float a = s_K[row][j] * s_x[j] + s_K[row][j + 64] * s_x[j + 64] +
                s_K[row][j + 128] * s_x[j + 128] + s_K[row][j + 192] * s_x[j + 192];
      a = wred64(a);
      if (j == 0) s_pub[136 + row] = a;
    }
    __syncthreads();
    if (tid < 37) st4_byp(exch + ((size_t)par * 32 + r) * EROW + tid * 4,
                          *(const f4*)&s_pub[tid * 4]);
    if (tid < 64) {
      waitvm();
      if (tid < 32) stflag(&flags[(r * 32 + tid) * 16], want);
    }

    // ===== slack(t): vectorized pre-scans + LDS-table window convolutions =====
    const int shi = (t & ~7) - 3;   // pre-scan upper bound (visibility-safe)
    {  // PreV partials: ages (t+7-s), target T_v = t+8 (f4 over whT rows)
      const int d = tid & 255, grp = tid >> 8;
      const float* wr = whT + (size_t)d * 256;
      float a = 0.f;
      for (int s0 = grp * 4; s0 + 3 <= shi; s0 += 8) {
        const f4 w4 = *(const f4*)(wr + s0);
        a = fmaf(w4[0], s_phiT[t + 7 - s0], a);
        a = fmaf(w4[1], s_phiT[t + 6 - s0], a);
        a = fmaf(w4[2], s_phiT[t + 5 - s0], a);
        a = fmaf(w4[3], s_phiT[t + 4 - s0], a);
      }
      if (grp == 0 && shi >= 0) {
        for (int s = (shi + 1) & ~3; s <= shi; ++s)
          a = fmaf(wr[s], s_phiT[t + 7 - s], a);
      }
      s_pvp[grp][d] = a;
    }
    {  // Fwin: ages (t+1-s), s in [wlo, t-1], from u-ring (LDS)
      const int nn = tid >> 2, kb = (tid & 3) * 5;
      int wlo = ((t + 1) & ~7) - 10; if (wlo < 0) wlo = 0;
      float p5[5] = {0.f, 0.f, 0.f, 0.f, 0.f};
      for (int s = wlo; s <= t - 1; ++s) {
        const float uu = s_uring[s & 31][nn];
        const int age = t + 1 - s;
#pragma unroll
        for (int i = 0; i < 5; ++i) p5[i] = fmaf(uu, s_phisT[kb + i][age], p5[i]);
      }
#pragma unroll
      for (int i = 0; i < 5; ++i) s_PP[kb + i][nn] = p5[i];
    }
    __syncthreads();
    {  // Fwin fold -> s_fold (own 8 d)
      const int row = tid >> 6, lane = tid & 63;
      float f = 0.f;
      for (int m = lane; m < 2560; m += 64) {
        const int k = m >> 7, nn = m & 127;
        f = fmaf(Ms[((size_t)k * 256 + d0 + row) * 128 + nn], s_PP[k][nn], f);
      }
      f = wred64(f);
      if (lane == 0) s_fold[row] = f;
    }
    if (t >= 1 && ((t - 1) & 31) == r) {  // deferred loss(t-1) from stash
      const int d = tid >> 1, half = tid & 1;
      const float* qr = Qmat + (size_t)d * 256 + half * 128;
      float qa = 0.f;
#pragma unroll 16
      for (int j = 0; j < 128; ++j) qa = fmaf(qr[j], s_lx[half * 128 + j], qa);
      qa += __shfl_xor(qa, 1);
      float tot = (half == 0) ? qa * s_lx[d] : 0.f;
      {
        const float* rr2 = Rm + (size_t)(tid >> 2) * 128 + (tid & 3) * 32;
        float ra = 0.f;
#pragma unroll
        for (int j = 0; j < 32; ++j) ra = fmaf(rr2[j], s_lu[(tid & 3) * 32 + j], ra);
        ra += __shfl_xor(ra, 1); ra += __shfl_xor(ra, 2);
        if ((tid & 3) == 0) tot += ra * s_lu[tid >> 2];
      }
      tot = wred64(tot);
      if ((tid & 63) == 0) s_red[tid >> 6] = tot;
      __syncthreads();
      if (tid == 0) {
        float ss = 0.f;
        for (int i3 = 0; i3 < 8; ++i3) ss += s_red[i3];
        out[t - 1] = ss;
      }
    }
    __syncthreads();
    {  // PPpre: ages (t+8-s), s <= shi (f4 over uhT rows + LDS phis table)
      const int nn = tid >> 2, kb = (tid & 3) * 5;
      const float* ur = uhT + (size_t)nn * 256;
      float p5[5] = {0.f, 0.f, 0.f, 0.f, 0.f};
      for (int s0 = 0; s0 + 3 <= shi; s0 += 4) {
        const f4 u4 = *(const f4*)(ur + s0);
#pragma unroll
        for (int j = 0; j < 4; ++j) {
          const int age = t + 8 - s0 - j;
#pragma unroll
          for (int i = 0; i < 5; ++i) p5[i] = fmaf(u4[j], s_phisT[kb + i][age], p5[i]);
        }
      }
      if (shi >= 0) {
        for (int s = (shi + 1) & ~3; s <= shi; ++s) {
          const float uu = ur[s];
          const int age = t + 8 - s;
#pragma unroll
          for (int i = 0; i < 5; ++i) p5[i] = fmaf(uu, s_phisT[kb + i][age], p5[i]);
        }
      }
#pragma unroll
      for (int i = 0; i < 5; ++i) s_PP[kb + i][nn] = p5[i];
    }
    __syncthreads();
    {  // XP fold -> s_XP[own d][t&7]
      const int row = tid >> 6, lane = tid & 63;
      float f = 0.f;
      for (int m = lane; m < 2560; m += 64) {
        const int k = m >> 7, nn = m & 127;
        f = fmaf(Ms[((size_t)k * 256 + d0 + row) * 128 + nn], s_PP[k][nn], f);
      }
      f = wred64(f);
      if (lane == 0) s_XP[row][t & 7] = f;
    }

    // ===== poll: 1 poller per replica-flag line =====
    if (tid < 32) {
      const unsigned* fp = &flags[(tid * 32 + r) * 16];
      int guard = 0;
      while (ldflag(fp) < want && ++guard < SPIN_CAP) {}
    }
    __syncthreads();

    // ===== gather: 1184 dwordx4, staggered by producer =====
    {
      const int i0 = tid, i1 = tid + 512, i2 = tid + 1024;
      const int p0 = i0 / 37, c0 = i0 - p0 * 37;
      const int p1 = i1 / 37, c1 = i1 - p1 * 37;
      const int pp0 = (p0 + r) & 31, pp1 = (p1 + r) & 31;
      f4 a0 = ld4_byp(exch + ((size_t)par * 32 + pp0) * EROW + c0 * 4);
      f4 a1 = ld4_byp(exch + ((size_t)par * 32 + pp1) * EROW + c1 * 4);
      f4 a2;
      int pp2 = 0, c2 = 0;
      if (i2 < 1184) {
        const int p2 = i2 / 37; c2 = i2 - p2 * 37; pp2 = (p2 + r) & 31;
        a2 = ld4_byp(exch + ((size_t)par * 32 + pp2) * EROW + c2 * 4);
      }
      waitvm();
      *(f4*)&s_gbuf[pp0][c0 * 4] = a0;
      *(f4*)&s_gbuf[pp1][c1 * 4] = a1;
      if (i2 < 1184) *(f4*)&s_gbuf[pp2][c2 * 4] = a2;
    }
    __syncthreads();

    // ===== post(t): u, g, w, x_{t+1}, v_{t+1}, next xold =====
    if (tid < 128) {
      float s = 0.f;
#pragma unroll 8
      for (int p = 0; p < 32; ++p) s += s_gbuf[p][tid];
      s -= s_gbuf[tid >> 2][136 + (tid & 3)];
      s_u[tid] = s;
      s_uring[t & 31][tid] = s;
      if (r == 0) st1_byp(uhT + (size_t)tid * 256 + t, s);
    }
    __syncthreads();
    if ((t & 31) == r && tid < 256) {   // stash x_t, u_t for deferred loss
      s_lx[tid] = s_x[tid];
      if (tid < 128) s_lu[tid] = s_u[tid];
    }
    {  // g_t = 2 R u_t
      float a = 0.f;
      const float* rr = Rm + (size_t)n * 128 + dsub * 32;
#pragma unroll
      for (int j2 = 0; j2 < 32; ++j2) a = fmaf(rr[j2], s_u[dsub * 32 + j2], a);
      a += __shfl_xor(a, 1); a += __shfl_xor(a, 2);
      if (dsub == 0) s_g[n] = 2.f * a;
    }
    {  // SB·u, S0·u -> w_t, x_{t+1} (replicated)
      const int d = tid >> 1, half = tid & 1;
      const float* sbr = SBsh + (size_t)d * 128 + half * 64;
      const float* s0r = S0sh + (size_t)d * 128 + half * 64;
      const float* ur = s_u + half * 64;
      float asb = 0.f, as0 = 0.f;
#pragma unroll
      for (int j2 = 0; j2 < 64; ++j2) {
        asb = fmaf(sbr[j2], ur[j2], asb);
        as0 = fmaf(s0r[j2], ur[j2], as0);
      }
      asb += __shfl_xor(asb, 1); as0 += __shfl_xor(as0, 1);
      if (half == 0) {
        const float xo = s_gbuf[d >> 3][140 + (d & 7)];
        const float ax = s_gbuf[d >> 3][128 + (d & 7)];
        const float wv = xo + asb - ax;
        s_wring[t & 31][d] = wv;
        s_xn[d] = xo + as0;
        if (r == 0) st1_byp(whT + (size_t)d * 256 + t, wv);
      }
    }
    if (tid < 256) s_PreV[tid][t & 7] = s_pvp[0][tid] + s_pvp[1][tid];
    __syncthreads();
    if (tid < 256) {  // x update + v_{t+1} assembly (pre + window + W0 term)
      const int d = tid, T = t + 1;
      s_x[d] = s_xn[d];
      int lo = (T & ~7) - 10; if (lo < 0) lo = 0;
      float v = s_PreV[d][T & 7] + s_W0[d] * s_phiT[T];
      for (int s = lo; s <= t; ++s)
        v = fmaf(s_wring[s & 31][d], s_phiT[t - s], v);
      s_vb[T & 1][d >> 6][d & 63] = v;
    }
    {  // xold for round t+1: XP-pre + window-fold + S1·u_t
      const int row = tid >> 6, j = tid & 63;
      float a = s_S1[row][j] * s_u[j] + s_S1[row][j + 64] * s_u[j + 64];
      a = wred64(a);
      if (j == 0) s_pub[140 + row] = s_XP[row][(t + 1) & 7] + s_fold[row] + a;
    }
    waitvm();   // drain whT/uhT/exch stores -> flag chain orders them for readers
    __syncthreads();
  }

  // ---------------- final deferred loss (t = 255, r = 31) ----------------
  if (((Tt - 1) & 31) == r) {
    const int d = tid >> 1, half = tid & 1;
    const float* qr = Qmat + (size_t)d * 256 + half * 128;
    float qa = 0.f;
#pragma unroll 16
    for (int j = 0; j < 128; ++j) qa = fmaf(qr[j], s_lx[half * 128 + j], qa);
    qa += __shfl_xor(qa, 1);
    float tot = (half == 0) ? qa * s_lx[d] : 0.f;
    {
      const float* rr2 = Rm + (size_t)(tid >> 2) * 128 + (tid & 3) * 32;
      float ra = 0.f;
#pragma unroll
      for (int j = 0; j < 32; ++j) ra = fmaf(rr2[j], s_lu[(tid & 3) * 32 + j], ra);
      ra += __shfl_xor(ra, 1); ra += __shfl_xor(ra, 2);
      if ((tid & 3) == 0) tot += ra * s_lu[tid >> 2];
    }
    tot = wred64(tot);
    if ((tid & 63) == 0) s_red[tid >> 6] = tot;
    __syncthreads();
    if (tid == 0) {
      float ss = 0.f;
      for (int i3 = 0; i3 < 8; ++i3) ss += s_red[i3];
      out[Tt - 1] = ss;
    }
  }
}

extern "C" void kernel_launch(void* const* d_in, const int* in_sizes, int n_in,
                              void* d_out, int out_size, void* d_ws, size_t ws_size,
                              hipStream_t stream) {
  (void)in_sizes; (void)n_in; (void)out_size; (void)ws_size;
  const float* A   = (const float*)d_in[0];
  const float* B   = (const float*)d_in[1];
  const float* Qm  = (const float*)d_in[2];
  const float* R   = (const float*)d_in[3];
  const float* K   = (const float*)d_in[4];
  const float* phi = (const float*)d_in[5];
  const float* sig = (const float*)d_in[6];
  const float* phs = (const float*)d_in[7];
  const float* M0  = (const float*)d_in[8];
  const float* Ms  = (const float*)d_in[9];
  const float* x0  = (const float*)d_in[10];
  const float* W0  = (const float*)d_in[11];
  // d_in[12] = U0 (zeros, unused)

  // replica flags must be re-zeroed every call (monotone tags)
  init_ws_kernel<<<64, 256, 0, stream>>>((unsigned*)d_ws);
  osf_main<<<NWG, NT, 0, stream>>>(A, B, Qm, R, K, phi, sig, phs, M0, Ms, x0, W0,
                                   (float*)d_out, (char*)d_ws);
}

// Round 11
// 5992.756 us; speedup vs baseline: 1.9635x; 1.9505x over previous
//
#include <hip/hip_runtime.h>

#define Tt 256
#define NWG 32
#define NT 512
#define ETAf 1e-3f
#define SPIN_CAP (1 << 24)
#define EROW 232

typedef float f4 __attribute__((ext_vector_type(4)));

// ---------------- ws layout (byte offsets) ----------------
// flags: u32[32*32*16] @0 (64KB, zeroed per call); exch: f32[2][32][EROW] @65536 (59.4KB);
// S0sh @131072 (128KB); SBsh @262144 (128KB); whist[s][d] row-major @393216 (256KB).

__device__ __forceinline__ unsigned ldflag(const unsigned* p) {
  return __hip_atomic_load(p, __ATOMIC_RELAXED, __HIP_MEMORY_SCOPE_AGENT);
}
__device__ __forceinline__ void stflag(unsigned* p, unsigned v) {
  __hip_atomic_store(p, v, __ATOMIC_RELAXED, __HIP_MEMORY_SCOPE_AGENT);
}
__device__ __forceinline__ f4 ld4_byp(const float* p) {
  f4 r;
  asm volatile("global_load_dwordx4 %0, %1, off sc0 sc1" : "=v"(r) : "v"(p) : "memory");
  return r;
}
__device__ __forceinline__ void st4_byp(float* p, f4 v) {
  asm volatile("global_store_dwordx4 %0, %1, off sc0 sc1" :: "v"(p), "v"(v) : "memory");
}
__device__ __forceinline__ void st1_byp(float* p, float v) {
  asm volatile("global_store_dword %0, %1, off sc0 sc1" :: "v"(p), "v"(v) : "memory");
}
__device__ __forceinline__ void waitvm() { asm volatile("s_waitcnt vmcnt(0)" ::: "memory"); }
__device__ __forceinline__ float wred64(float p) {
  p += __shfl_xor(p, 1); p += __shfl_xor(p, 2); p += __shfl_xor(p, 4);
  p += __shfl_xor(p, 8); p += __shfl_xor(p, 16); p += __shfl_xor(p, 32);
  return p;
}

__global__ void init_ws_kernel(unsigned* w) {
  const int i = blockIdx.x * 256 + threadIdx.x;
  if (i < 32 * 32 * 16) w[i] = 0u;
}

__global__ __launch_bounds__(NT, 1)
void osf_main(const float* __restrict__ Am, const float* __restrict__ Bm,
              const float* __restrict__ Qmat, const float* __restrict__ Rm,
              const float* __restrict__ Km, const float* __restrict__ phi,
              const float* __restrict__ sigma, const float* __restrict__ phis,
              const float* __restrict__ M0, const float* __restrict__ Ms,
              const float* __restrict__ x0, const float* __restrict__ W0,
              float* __restrict__ out, char* __restrict__ ws) {
  unsigned* flags = (unsigned*)ws;
  float* exch  = (float*)(ws + 65536);
  float* S0sh  = (float*)(ws + 131072);
  float* SBsh  = (float*)(ws + 262144);
  float* whist = (float*)(ws + 393216);   // [256 s][256 d] row-major

  const int r = blockIdx.x, tid = threadIdx.x;
  const int n = tid >> 2, dsub = tid & 3;   // M layout: M[r][n][dsub*64+e]
  const int d0 = r * 8;                     // owned d rows
  const float s4h = sqrtf(sqrtf(sigma[r]));

  __shared__ float s_gbuf[32][EROW];   // gathered exchange
  __shared__ float s_wring[32][256];   // w history ring (v window)
  __shared__ float s_uown[4][256];     // own-n u full history
  __shared__ float s_PreV[256][8];     // v-conv pre-block [d][tau]
  __shared__ float s_pvp8[8][256];     // PreV partials by s-group
  __shared__ float s_phisT[20][289];   // phis transposed [k][age], padded stride
  __shared__ float s_phiT[288];        // own-h phi column [age]
  __shared__ float s_PFn[20][4];       // PF bulk (slack -> post)
  __shared__ float s_A[8][256];        // A own rows
  __shared__ float s_K[4][256];        // K own rows
  __shared__ float s_S1[8][128];       // phis-row-1 fold of Ms, own d
  __shared__ float s_vb[2][4][65];     // v double buffer (padded)
  __shared__ float s_x[256], s_xn[256], s_W0[256], s_lx[256];
  __shared__ float s_u[128], s_g[128], s_lu[128];
  __shared__ float s_pub[228];
  __shared__ float s_fold[8], s_red[8];

  // ---------------- init ----------------
  for (int i = tid; i < 2048; i += NT) ((float*)s_A)[i] = Am[(size_t)d0 * 256 + i];
  for (int i = tid; i < 1024; i += NT) ((float*)s_K)[i] = Km[(size_t)(4 * r) * 256 + i];
  for (int i = tid; i < 256; i += NT) {
    s_W0[i] = W0[(size_t)i * 512];
    s_x[i] = x0[i];
  }
  for (int i = tid; i < 2048; i += NT) ((float*)s_PreV)[i] = 0.f;
  for (int i = tid; i < 520; i += NT) ((float*)s_vb)[i] = 0.f;
  for (int i = tid; i < 228; i += NT) s_pub[i] = 0.f;   // cn/xold/PF slots start 0
  for (int i = tid; i < 20 * 289; i += NT) {   // phis transposed by age (padded)
    const int k = i / 289, age = i - k * 289;
    s_phisT[k][age] = phis[(size_t)age * 20 + k];
  }
  for (int i = tid; i < 288; i += NT) s_phiT[i] = phi[(size_t)i * 32 + r];
  for (int i = tid; i < 1024; i += NT) {   // S1 own + shared S0/SB (bypass)
    const int row = i >> 7, nn = i & 127;
    float a0 = 0.f, a1 = 0.f;
    for (int k = 0; k < 20; ++k) {
      const float m = Ms[((size_t)k * 256 + d0 + row) * 128 + nn];
      a0 = fmaf(phis[k], m, a0);
      a1 = fmaf(phis[20 + k], m, a1);
    }
    s_S1[row][nn] = a1;
    st1_byp(S0sh + (size_t)(d0 + row) * 128 + nn, a0);
    st1_byp(SBsh + (size_t)(d0 + row) * 128 + nn, a0 - Bm[(size_t)(d0 + row) * 128 + nn]);
  }
  float Mreg[64];
  {
    const float* mp = M0 + ((size_t)r * 128 + n) * 256 + dsub * 64;
#pragma unroll
    for (int e = 0; e < 64; ++e) Mreg[e] = mp[e];
  }
  waitvm();
  __syncthreads();
  if (tid < 256) s_vb[0][tid >> 6][tid & 63] = s_W0[tid] * s_phiT[0];   // v_0
  __syncthreads();
  if (tid < 32) stflag(&flags[(r * 32 + tid) * 16], 1u);
  if (tid < 32) {   // init poll: S0/SB visibility
    const unsigned* fp = &flags[(tid * 32 + r) * 16];
    int guard = 0;
    while (ldflag(fp) < 1u && ++guard < SPIN_CAP) {}
  }
  __syncthreads();

  // ---------------- main loop: ONE exchange per step ----------------
  for (int t = 0; t < Tt; ++t) {
    const unsigned want = (unsigned)(t + 2);
    const int par = t & 1;

    // ===== publish(t): [cnp 0..127 | Ax 128..135 | Kx 136..139 | xold 140..147 | PF 148..227]
    {
      float coef = (t > 0) ? (ETAf * s4h * s_g[n]) : 0.f;
      const float* vc = &s_vb[par][dsub][0];
      const float* vpv = &s_vb[par ^ 1][dsub][0];
      float acc = 0.f;
#pragma unroll
      for (int e = 0; e < 64; ++e) {
        Mreg[e] = fmaf(-coef, vpv[e], Mreg[e]);
        acc = fmaf(Mreg[e], vc[e], acc);
      }
      acc += __shfl_xor(acc, 1); acc += __shfl_xor(acc, 2);
      if (dsub == 0) s_pub[n] = s4h * acc;
    }
    {  // Ax own 8 rows
      const int row = tid >> 6, j = tid & 63;
      float a = s_A[row][j] * s_x[j] + s_A[row][j + 64] * s_x[j + 64] +
                s_A[row][j + 128] * s_x[j + 128] + s_A[row][j + 192] * s_x[j + 192];
      a = wred64(a);
      if (j == 0) s_pub[128 + row] = a;
    }
    if (tid < 256) {  // Kx own 4 rows
      const int row = tid >> 6, j = tid & 63;
      float a = s_K[row][j] * s_x[j] + s_K[row][j + 64] * s_x[j + 64] +
                s_K[row][j + 128] * s_x[j + 128] + s_K[row][j + 192] * s_x[j + 192];
      a = wred64(a);
      if (j == 0) s_pub[136 + row] = a;
    }
    __syncthreads();
    if (tid < 57) st4_byp(exch + ((size_t)par * 32 + r) * EROW + tid * 4,
                          *(const f4*)&s_pub[tid * 4]);
    if (tid < 64) {
      waitvm();
      if (tid < 32) stflag(&flags[(r * 32 + tid) * 16], want);
    }

    // ===== slack(t): thin, distributed =====
    const int shi = (t & ~7) - 3;   // visibility-safe pre-scan bound
    {  // PreV partials: f4 over d, row-major whist (plain cached loads, lines final)
      const int dq = tid & 63, sg = tid >> 6;
      f4 acc = {0.f, 0.f, 0.f, 0.f};
      for (int s = sg; s <= shi; s += 8) {
        const f4 w4 = *(const f4*)(whist + (size_t)s * 256 + dq * 4);
        const float ph = s_phiT[t + 7 - s];
        acc[0] = fmaf(w4[0], ph, acc[0]);
        acc[1] = fmaf(w4[1], ph, acc[1]);
        acc[2] = fmaf(w4[2], ph, acc[2]);
        acc[3] = fmaf(w4[3], ph, acc[3]);
      }
      *(f4*)&s_pvp8[sg][dq * 4] = acc;
    }
    if (tid < 320) {  // PF bulk for publish(t+1): own 4n x 20k, ages (t+2)-s, s<=t-1
      const int nn = tid / 80, rem = tid % 80, k = rem >> 2, sub = rem & 3;
      float a = 0.f;
      for (int s = sub; s <= t - 1; s += 4)
        a = fmaf(s_uown[nn][s], s_phisT[k][t + 2 - s], a);
      a += __shfl_xor(a, 1);
      a += __shfl_xor(a, 2);
      if (sub == 0) s_PFn[k][nn] = a;
    }
    if (t >= 1 && ((t - 1) & 31) == r) {  // deferred loss(t-1) from stash
      const int d = tid >> 1, half = tid & 1;
      const float* qr = Qmat + (size_t)d * 256 + half * 128;
      float qa = 0.f;
#pragma unroll 16
      for (int j = 0; j < 128; ++j) qa = fmaf(qr[j], s_lx[half * 128 + j], qa);
      qa += __shfl_xor(qa, 1);
      float tot = (half == 0) ? qa * s_lx[d] : 0.f;
      {
        const float* rr2 = Rm + (size_t)(tid >> 2) * 128 + (tid & 3) * 32;
        float ra = 0.f;
#pragma unroll
        for (int j = 0; j < 32; ++j) ra = fmaf(rr2[j], s_lu[(tid & 3) * 32 + j], ra);
        ra += __shfl_xor(ra, 1); ra += __shfl_xor(ra, 2);
        if ((tid & 3) == 0) tot += ra * s_lu[tid >> 2];
      }
      tot = wred64(tot);
      if ((tid & 63) == 0) s_red[tid >> 6] = tot;
      __syncthreads();
      if (tid == 0) {
        float ss = 0.f;
        for (int i3 = 0; i3 < 8; ++i3) ss += s_red[i3];
        out[t - 1] = ss;
      }
    }

    // ===== poll: 1 poller per replica-flag line =====
    if (tid < 32) {
      const unsigned* fp = &flags[(tid * 32 + r) * 16];
      int guard = 0;
      while (ldflag(fp) < want && ++guard < SPIN_CAP) {}
    }
    __syncthreads();

    // ===== gather: 1824 dwordx4, staggered by producer =====
    {
      const int i0 = tid, i1 = tid + 512, i2 = tid + 1024, i3 = tid + 1536;
      const int p0 = i0 / 57, c0 = i0 - p0 * 57;
      const int p1 = i1 / 57, c1 = i1 - p1 * 57;
      const int p2 = i2 / 57, c2 = i2 - p2 * 57;
      const int pp0 = (p0 + r) & 31, pp1 = (p1 + r) & 31, pp2 = (p2 + r) & 31;
      f4 a0 = ld4_byp(exch + ((size_t)par * 32 + pp0) * EROW + c0 * 4);
      f4 a1 = ld4_byp(exch + ((size_t)par * 32 + pp1) * EROW + c1 * 4);
      f4 a2 = ld4_byp(exch + ((size_t)par * 32 + pp2) * EROW + c2 * 4);
      f4 a3;
      int pp3 = 0, c3 = 0;
      if (i3 < 1824) {
        const int p3 = i3 / 57; c3 = i3 - p3 * 57; pp3 = (p3 + r) & 31;
        a3 = ld4_byp(exch + ((size_t)par * 32 + pp3) * EROW + c3 * 4);
      }
      waitvm();
      *(f4*)&s_gbuf[pp0][c0 * 4] = a0;
      *(f4*)&s_gbuf[pp1][c1 * 4] = a1;
      *(f4*)&s_gbuf[pp2][c2 * 4] = a2;
      if (i3 < 1824) *(f4*)&s_gbuf[pp3][c3 * 4] = a3;
    }
    __syncthreads();

    // ===== post(t) =====
    {  // fold gathered P'' against own Ms rows -> s_fold
      const int row = tid >> 6, lane = tid & 63;
      float f = 0.f;
      for (int m = lane; m < 2560; m += 64) {
        const int k = m >> 7, nc = m & 127;
        f = fmaf(Ms[((size_t)k * 256 + d0 + row) * 128 + nc],
                 s_gbuf[nc >> 2][148 + k * 4 + (nc & 3)], f);
      }
      f = wred64(f);
      if (lane == 0) s_fold[row] = f;
    }
    if (tid < 128) {  // u_t assembly
      float s = 0.f;
#pragma unroll 8
      for (int p = 0; p < 32; ++p) s += s_gbuf[p][tid];
      s -= s_gbuf[tid >> 2][136 + (tid & 3)];
      s_u[tid] = s;
    }
    __syncthreads();
    if (tid < 4) s_uown[tid][t] = s_u[4 * r + tid];
    if ((t & 31) == r && tid < 256) {   // stash x_t, u_t for deferred loss
      s_lx[tid] = s_x[tid];
      if (tid < 128) s_lu[tid] = s_u[tid];
    }
    {  // g_t = 2 R u_t
      float a = 0.f;
      const float* rr = Rm + (size_t)n * 128 + dsub * 32;
#pragma unroll
      for (int j2 = 0; j2 < 32; ++j2) a = fmaf(rr[j2], s_u[dsub * 32 + j2], a);
      a += __shfl_xor(a, 1); a += __shfl_xor(a, 2);
      if (dsub == 0) s_g[n] = 2.f * a;
    }
    {  // SB·u, S0·u -> w_t, x_{t+1} (replicated)
      const int d = tid >> 1, half = tid & 1;
      const float* sbr = SBsh + (size_t)d * 128 + half * 64;
      const float* s0r = S0sh + (size_t)d * 128 + half * 64;
      const float* ur = s_u + half * 64;
      float asb = 0.f, as0 = 0.f;
#pragma unroll
      for (int j2 = 0; j2 < 64; ++j2) {
        asb = fmaf(sbr[j2], ur[j2], asb);
        as0 = fmaf(s0r[j2], ur[j2], as0);
      }
      asb += __shfl_xor(asb, 1); as0 += __shfl_xor(as0, 1);
      if (half == 0) {
        const float xo = s_gbuf[d >> 3][140 + (d & 7)];
        const float ax = s_gbuf[d >> 3][128 + (d & 7)];
        const float wv = xo + asb - ax;
        s_wring[t & 31][d] = wv;
        s_xn[d] = xo + as0;
        if (r == 0) st1_byp(whist + (size_t)t * 256 + d, wv);
      }
    }
    if (tid < 80) {  // PF exchange slot: bulk + newest u_t term (age 2)
      const int k = tid >> 2, nn = tid & 3;
      s_pub[148 + k * 4 + nn] = s_PFn[k][nn] + s_u[4 * r + nn] * s_phisT[k][2];
    }
    if (tid < 256) {  // PreV combine
      float v = s_pvp8[0][tid];
#pragma unroll
      for (int sg = 1; sg < 8; ++sg) v += s_pvp8[sg][tid];
      s_PreV[tid][t & 7] = v;
    }
    __syncthreads();
    if (tid < 256) {  // x update + v_{t+1} assembly (pre + window + W0 term)
      const int d = tid, T = t + 1;
      s_x[d] = s_xn[d];
      int lo = (T & ~7) - 10; if (lo < 0) lo = 0;
      float v = s_PreV[d][T & 7] + s_W0[d] * s_phiT[T];
      for (int s = lo; s <= t; ++s)
        v = fmaf(s_wring[s & 31][d], s_phiT[t - s], v);
      s_vb[T & 1][d >> 6][d & 63] = v;
    }
    {  // xold for publish(t+1): gathered-fold + S1·u_t (age 1)
      const int row = tid >> 6, j = tid & 63;
      float a = s_S1[row][j] * s_u[j] + s_S1[row][j + 64] * s_u[j + 64];
      a = wred64(a);
      if (j == 0) s_pub[140 + row] = s_fold[row] + a;
    }
    waitvm();   // drain whist stores -> flag chain orders them for readers
    __syncthreads();
  }

  // ---------------- final deferred loss (t = 255, r = 31) ----------------
  if (((Tt - 1) & 31) == r) {
    const int d = tid >> 1, half = tid & 1;
    const float* qr = Qmat + (size_t)d * 256 + half * 128;
    float qa = 0.f;
#pragma unroll 16
    for (int j = 0; j < 128; ++j) qa = fmaf(qr[j], s_lx[half * 128 + j], qa);
    qa += __shfl_xor(qa, 1);
    float tot = (half == 0) ? qa * s_lx[d] : 0.f;
    {
      const float* rr2 = Rm + (size_t)(tid >> 2) * 128 + (tid & 3) * 32;
      float ra = 0.f;
#pragma unroll
      for (int j = 0; j < 32; ++j) ra = fmaf(rr2[j], s_lu[(tid & 3) * 32 + j], ra);
      ra += __shfl_xor(ra, 1); ra += __shfl_xor(ra, 2);
      if ((tid & 3) == 0) tot += ra * s_lu[tid >> 2];
    }
    tot = wred64(tot);
    if ((tid & 63) == 0) s_red[tid >> 6] = tot;
    __syncthreads();
    if (tid == 0) {
      float ss = 0.f;
      for (int i3 = 0; i3 < 8; ++i3) ss += s_red[i3];
      out[Tt - 1] = ss;
    }
  }
}

extern "C" void kernel_launch(void* const* d_in, const int* in_sizes, int n_in,
                              void* d_out, int out_size, void* d_ws, size_t ws_size,
                              hipStream_t stream) {
  (void)in_sizes; (void)n_in; (void)out_size; (void)ws_size;
  const float* A   = (const float*)d_in[0];
  const float* B   = (const float*)d_in[1];
  const float* Qm  = (const float*)d_in[2];
  const float* R   = (const float*)d_in[3];
  const float* K   = (const float*)d_in[4];
  const float* phi = (const float*)d_in[5];
  const float* sig = (const float*)d_in[6];
  const float* phs = (const float*)d_in[7];
  const float* M0  = (const float*)d_in[8];
  const float* Ms  = (const float*)d_in[9];
  const float* x0  = (const float*)d_in[10];
  const float* W0  = (const float*)d_in[11];
  // d_in[12] = U0 (zeros, unused)

  // replica flags must be re-zeroed every call (monotone tags)
  init_ws_kernel<<<64, 256, 0, stream>>>((unsigned*)d_ws);
  osf_main<<<NWG, NT, 0, stream>>>(A, B, Qm, R, K, phi, sig, phs, M0, Ms, x0, W0,
                                   (float*)d_out, (char*)d_ws);
}